// Round 1
// baseline (202.832 us; speedup 1.0000x reference)
//
#include <hip/hip_runtime.h>
#include <stdint.h>

#define B_ 4
#define T_ 4096
#define D_ 512
#define H_ 8
#define HD_ 64
#define W_ 5
#define M_ (B_*T_)     // 16384 rows
#define N_ (3*D_)      // 1536 cols (Q|K|V)

typedef __attribute__((ext_vector_type(8))) short short8;
typedef __attribute__((ext_vector_type(4))) float floatx4;

__device__ __forceinline__ unsigned short f2bf(float f) {
    unsigned int u = __builtin_bit_cast(unsigned int, f);
    u += 0x7fffu + ((u >> 16) & 1u);          // RNE
    return (unsigned short)(u >> 16);
}
__device__ __forceinline__ float bf2f(unsigned short s) {
    unsigned int u = ((unsigned int)s) << 16;
    return __builtin_bit_cast(float, u);
}
__device__ __forceinline__ void load8bf(const unsigned short* p, float* f) {
    uint4 d = *(const uint4*)p;
    f[0] = bf2f((unsigned short)(d.x & 0xffffu));
    f[1] = bf2f((unsigned short)(d.x >> 16));
    f[2] = bf2f((unsigned short)(d.y & 0xffffu));
    f[3] = bf2f((unsigned short)(d.y >> 16));
    f[4] = bf2f((unsigned short)(d.z & 0xffffu));
    f[5] = bf2f((unsigned short)(d.z >> 16));
    f[6] = bf2f((unsigned short)(d.w & 0xffffu));
    f[7] = bf2f((unsigned short)(d.w >> 16));
}

// ---------------- convert X (fp32 -> bf16), 8 elems/thread ----------------
__global__ __launch_bounds__(256) void convert_x(const float* __restrict__ x,
                                                 unsigned short* __restrict__ xb) {
    int i = blockIdx.x * 256 + threadIdx.x;      // exact: M_*512/8 threads
    const float4* x4 = (const float4*)x;
    float4 a = x4[2*i], b = x4[2*i + 1];
    uint4 o;
    o.x = (unsigned)f2bf(a.x) | ((unsigned)f2bf(a.y) << 16);
    o.y = (unsigned)f2bf(a.z) | ((unsigned)f2bf(a.w) << 16);
    o.z = (unsigned)f2bf(b.x) | ((unsigned)f2bf(b.y) << 16);
    o.w = (unsigned)f2bf(b.z) | ((unsigned)f2bf(b.w) << 16);
    ((uint4*)xb)[i] = o;
}

// ------------- build Wt[n][k] = W_proj[k][c] (transpose+convert) ----------
__global__ __launch_bounds__(256) void convert_w(const float* __restrict__ Wq,
                                                 const float* __restrict__ Wk,
                                                 const float* __restrict__ Wv,
                                                 unsigned short* __restrict__ Wt) {
    int tid = blockIdx.x * 256 + threadIdx.x;    // exact: 1536*64 threads
    int n  = tid % N_;                           // consecutive lanes -> consecutive c (coalesced reads)
    int kc = tid / N_;                           // k chunk of 8
    int proj = n >> 9, c = n & 511;
    const float* Wsrc = (proj == 0) ? Wq : ((proj == 1) ? Wk : Wv);
    unsigned short us[8];
#pragma unroll
    for (int j = 0; j < 8; j++)
        us[j] = f2bf(Wsrc[(size_t)(kc*8 + j) * D_ + c]);
    uint4 o;
    o.x = (unsigned)us[0] | ((unsigned)us[1] << 16);
    o.y = (unsigned)us[2] | ((unsigned)us[3] << 16);
    o.z = (unsigned)us[4] | ((unsigned)us[5] << 16);
    o.w = (unsigned)us[6] | ((unsigned)us[7] << 16);
    *(uint4*)(Wt + (size_t)n * D_ + kc*8) = o;
}

// ---------------- fused QKV GEMM: C[m][n] = X[m][:] . Wt[n][:] + bias -----
// 128x128 tile, BK=32, mfma_f32_16x16x32_bf16, LDS stride 40 bf16 (80B,
// 16B-aligned, bank-group walk (5r)%8 -> 2-way = free).
__global__ __launch_bounds__(256) void gemm_qkv(
    const unsigned short* __restrict__ Xb,   // [M_,512] bf16
    const unsigned short* __restrict__ Wt,   // [N_,512] bf16
    const float* __restrict__ bq, const float* __restrict__ bk2,
    const float* __restrict__ bv,
    unsigned short* __restrict__ Cb)         // [M_,N_] bf16
{
    constexpr int LDA = 40;
    __shared__ unsigned short As[128 * LDA];
    __shared__ unsigned short Bs[128 * LDA];
    const int tid = threadIdx.x;
    const int m0 = blockIdx.y * 128;
    const int n0 = blockIdx.x * 128;
    const int wave = tid >> 6, lane = tid & 63;
    const int wm = (wave >> 1) << 6, wn = (wave & 1) << 6;
    const int qd = lane >> 4, r16 = lane & 15;
    const int srow = tid >> 1, shalf = tid & 1;   // each thread stages 16 bf16/row-half

    floatx4 acc[4][4] = {};

    const uint4* xsrc = (const uint4*)(Xb + (size_t)(m0 + srow) * D_ + shalf*16);
    const uint4* wsrc = (const uint4*)(Wt + (size_t)(n0 + srow) * D_ + shalf*16);
    uint4* adst = (uint4*)(As + srow*LDA + shalf*16);
    uint4* bdst = (uint4*)(Bs + srow*LDA + shalf*16);

    for (int kc = 0; kc < D_; kc += 32) {
        uint4 a0 = xsrc[0], a1 = xsrc[1];
        uint4 b0 = wsrc[0], b1 = wsrc[1];
        xsrc += 4; wsrc += 4;                    // advance 32 bf16
        adst[0] = a0; adst[1] = a1;
        bdst[0] = b0; bdst[1] = b1;
        __syncthreads();

        short8 af[4], bf[4];
#pragma unroll
        for (int mi = 0; mi < 4; mi++)
            af[mi] = __builtin_bit_cast(short8,
                *(const uint4*)(As + (wm + mi*16 + r16)*LDA + qd*8));
#pragma unroll
        for (int ni = 0; ni < 4; ni++)
            bf[ni] = __builtin_bit_cast(short8,
                *(const uint4*)(Bs + (wn + ni*16 + r16)*LDA + qd*8));
#pragma unroll
        for (int mi = 0; mi < 4; mi++)
#pragma unroll
            for (int ni = 0; ni < 4; ni++)
                acc[mi][ni] = __builtin_amdgcn_mfma_f32_16x16x32_bf16(
                    af[mi], bf[ni], acc[mi][ni], 0, 0, 0);
        __syncthreads();
    }

    // epilogue: +bias, store bf16.  C/D layout: col=lane&15, row=(lane>>4)*4+r
#pragma unroll
    for (int ni = 0; ni < 4; ni++) {
        int col = n0 + wn + ni*16 + r16;
        float bias = (col < 512) ? bq[col] : ((col < 1024) ? bk2[col - 512] : bv[col - 1024]);
#pragma unroll
        for (int mi = 0; mi < 4; mi++) {
#pragma unroll
            for (int r = 0; r < 4; r++) {
                int row = m0 + wm + mi*16 + qd*4 + r;
                Cb[(size_t)row * N_ + col] = f2bf(acc[mi][ni][r] + bias);
            }
        }
    }
}

// ---------------- windowed attention ----------------
// one thread per (b,h,t).  pos_w = t + (shift_h + w - 2)*dil, masked iff OOB.
__global__ __launch_bounds__(256) void attn_kernel(
    const unsigned short* __restrict__ Cb,   // [M_,1536] bf16  (Q|K|V)
    const float* __restrict__ Er,            // [8,64,5] fp32
    const int* __restrict__ layer_p,
    float* __restrict__ out,                 // [B_,T_,512] fp32
    float* __restrict__ attn_out)            // [B_,8,T_,5] fp32
{
    __shared__ float sEr[HD_ * W_];          // 320 floats for this head
    const int bx = blockIdx.x;
    const int pair = bx >> 4;                // 16 blocks of 256 t's per (b,h)
    const int b = pair >> 3, h = pair & 7;
    const int t = (bx & 15) * 256 + threadIdx.x;

    for (int i = threadIdx.x; i < HD_ * W_; i += 256)
        sEr[i] = Er[h * HD_ * W_ + i];
    __syncthreads();

    const int layer = layer_p[0];
    const int dil = 1 << layer;
    const int sh = (h < 4) ? 0 : (h == 4 ? -2 : (h == 5 ? -1 : (h == 6 ? 1 : 2)));

    int pos[W_]; bool val[W_];
#pragma unroll
    for (int w = 0; w < W_; w++) {
        pos[w] = t + (sh + w - 2) * dil;
        val[w] = (pos[w] >= 0) && (pos[w] < T_);
    }

    const size_t browbase = (size_t)b * T_;
    const unsigned short* qrow  = Cb + (browbase + t) * N_ + h * HD_;
    const unsigned short* kbase = Cb + browbase * N_ + 512 + h * HD_;
    const unsigned short* vbase = Cb + browbase * N_ + 1024 + h * HD_;

    float qk[W_] = {0,0,0,0,0}, qe[W_] = {0,0,0,0,0};
#pragma unroll
    for (int dc = 0; dc < HD_; dc += 8) {
        float qf[8]; load8bf(qrow + dc, qf);
#pragma unroll
        for (int w = 0; w < W_; w++) {
            if (val[w]) {
                float kf[8]; load8bf(kbase + (size_t)pos[w] * N_ + dc, kf);
                float s = 0.f;
#pragma unroll
                for (int j = 0; j < 8; j++) s = fmaf(qf[j], kf[j], s);
                qk[w] += s;
            }
        }
#pragma unroll
        for (int j = 0; j < 8; j++)
#pragma unroll
            for (int w = 0; w < W_; w++)
                qe[w] = fmaf(qf[j], sEr[(dc + j) * W_ + w], qe[w]);
    }

    // softmax (masked terms == 0 exactly, matching fp32 exp underflow in ref)
    float logit[W_], mx = -1e30f;
#pragma unroll
    for (int w = 0; w < W_; w++) {
        logit[w] = val[w] ? (qk[w] + qe[w]) * 0.125f : -1e30f;
        mx = fmaxf(mx, logit[w]);
    }
    float p[W_], ssum = 0.f;
#pragma unroll
    for (int w = 0; w < W_; w++) {
        p[w] = val[w] ? __expf(logit[w] - mx) : 0.f;
        ssum += p[w];
    }
    const float inv = 1.f / ssum;
    float aw[W_];
    float* arow = attn_out + ((size_t)(b * H_ + h) * T_ + t) * W_;
#pragma unroll
    for (int w = 0; w < W_; w++) {
        aw[w] = p[w] * inv;
        arow[w] = aw[w];
    }

    // out = sum_w a_w * v_w
    float* orow = out + (browbase + t) * D_ + h * HD_;
#pragma unroll
    for (int dc = 0; dc < HD_; dc += 8) {
        float of[8] = {0,0,0,0,0,0,0,0};
#pragma unroll
        for (int w = 0; w < W_; w++) {
            if (val[w]) {
                float vf[8]; load8bf(vbase + (size_t)pos[w] * N_ + dc, vf);
#pragma unroll
                for (int j = 0; j < 8; j++) of[j] = fmaf(aw[w], vf[j], of[j]);
            }
        }
        *(float4*)(orow + dc)     = make_float4(of[0], of[1], of[2], of[3]);
        *(float4*)(orow + dc + 4) = make_float4(of[4], of[5], of[6], of[7]);
    }
}

extern "C" void kernel_launch(void* const* d_in, const int* in_sizes, int n_in,
                              void* d_out, int out_size, void* d_ws, size_t ws_size,
                              hipStream_t stream) {
    const float* x   = (const float*)d_in[0];
    const float* Wq  = (const float*)d_in[1];
    const float* bq  = (const float*)d_in[2];
    const float* Wk  = (const float*)d_in[3];
    const float* bk  = (const float*)d_in[4];
    const float* Wv  = (const float*)d_in[5];
    const float* bv  = (const float*)d_in[6];
    const float* Er  = (const float*)d_in[7];
    const int* layer = (const int*)d_in[8];

    char* ws = (char*)d_ws;
    unsigned short* Xb = (unsigned short*)ws;                               // 16 MB
    unsigned short* Wt = (unsigned short*)(ws + (size_t)16*1024*1024);      // 1.5 MB
    unsigned short* Cb = (unsigned short*)(ws + (size_t)18*1024*1024);      // 48 MB

    float* out  = (float*)d_out;
    float* attn = out + (size_t)B_ * T_ * D_;

    convert_x<<<(M_ * D_ / 8) / 256, 256, 0, stream>>>(x, Xb);
    convert_w<<<(N_ * (D_ / 8)) / 256, 256, 0, stream>>>(Wq, Wk, Wv, Wt);
    dim3 g(N_ / 128, M_ / 128);
    gemm_qkv<<<g, 256, 0, stream>>>(Xb, Wt, bq, bk, bv, Cb);
    attn_kernel<<<(B_ * H_ * T_) / 256, 256, 0, stream>>>(Cb, Er, layer, out, attn);
}

// Round 2
// 161.558 us; speedup vs baseline: 1.2555x; 1.2555x over previous
//
#include <hip/hip_runtime.h>
#include <stdint.h>

#define B_ 4
#define T_ 4096
#define D_ 512
#define H_ 8
#define HD_ 64
#define W_ 5
#define M_ (B_*T_)     // 16384 rows
#define N_ (3*D_)      // 1536 cols (Q|K|V)

typedef __attribute__((ext_vector_type(8))) short short8;
typedef __attribute__((ext_vector_type(4))) float floatx4;

__device__ __forceinline__ unsigned short f2bf(float f) {
    unsigned int u = __builtin_bit_cast(unsigned int, f);
    u += 0x7fffu + ((u >> 16) & 1u);          // RNE
    return (unsigned short)(u >> 16);
}
__device__ __forceinline__ float bf2f(unsigned short s) {
    unsigned int u = ((unsigned int)s) << 16;
    return __builtin_bit_cast(float, u);
}
__device__ __forceinline__ void load8bf(const unsigned short* p, float* f) {
    uint4 d = *(const uint4*)p;
    f[0] = bf2f((unsigned short)(d.x & 0xffffu));
    f[1] = bf2f((unsigned short)(d.x >> 16));
    f[2] = bf2f((unsigned short)(d.y & 0xffffu));
    f[3] = bf2f((unsigned short)(d.y >> 16));
    f[4] = bf2f((unsigned short)(d.z & 0xffffu));
    f[5] = bf2f((unsigned short)(d.z >> 16));
    f[6] = bf2f((unsigned short)(d.w & 0xffffu));
    f[7] = bf2f((unsigned short)(d.w >> 16));
}

// async global->LDS, 16B per lane; LDS dest = wave-uniform base + lane*16
__device__ __forceinline__ void async16(const unsigned short* g, unsigned short* l) {
    __builtin_amdgcn_global_load_lds(
        (const __attribute__((address_space(1))) unsigned int*)g,
        (__attribute__((address_space(3))) unsigned int*)l, 16, 0, 0);
}

// ---------------- convert X (fp32 -> bf16), 8 elems/thread ----------------
__global__ __launch_bounds__(256) void convert_x(const float* __restrict__ x,
                                                 unsigned short* __restrict__ xb) {
    int i = blockIdx.x * 256 + threadIdx.x;      // exact: M_*512/8 threads
    const float4* x4 = (const float4*)x;
    float4 a = x4[2*i], b = x4[2*i + 1];
    uint4 o;
    o.x = (unsigned)f2bf(a.x) | ((unsigned)f2bf(a.y) << 16);
    o.y = (unsigned)f2bf(a.z) | ((unsigned)f2bf(a.w) << 16);
    o.z = (unsigned)f2bf(b.x) | ((unsigned)f2bf(b.y) << 16);
    o.w = (unsigned)f2bf(b.z) | ((unsigned)f2bf(b.w) << 16);
    ((uint4*)xb)[i] = o;
}

// ------------- build Wt[n][k] = W_proj[k][c] (transpose+convert) ----------
__global__ __launch_bounds__(256) void convert_w(const float* __restrict__ Wq,
                                                 const float* __restrict__ Wk,
                                                 const float* __restrict__ Wv,
                                                 unsigned short* __restrict__ Wt) {
    int tid = blockIdx.x * 256 + threadIdx.x;    // exact: 1536*64 threads
    int n  = tid % N_;                           // consecutive lanes -> consecutive c
    int kc = tid / N_;                           // k chunk of 8
    int proj = n >> 9, c = n & 511;
    const float* Wsrc = (proj == 0) ? Wq : ((proj == 1) ? Wk : Wv);
    unsigned short us[8];
#pragma unroll
    for (int j = 0; j < 8; j++)
        us[j] = f2bf(Wsrc[(size_t)(kc*8 + j) * D_ + c]);
    uint4 o;
    o.x = (unsigned)us[0] | ((unsigned)us[1] << 16);
    o.y = (unsigned)us[2] | ((unsigned)us[3] << 16);
    o.z = (unsigned)us[4] | ((unsigned)us[5] << 16);
    o.w = (unsigned)us[6] | ((unsigned)us[7] << 16);
    *(uint4*)(Wt + (size_t)n * D_ + kc*8) = o;
}

// ---------------- fused QKV GEMM (m97 structure) --------------------------
// 128x128 tile, BK=32, mfma_f32_16x16x32_bf16.
// LDS tiles UNPADDED [128][32] bf16 (64B rows) so global_load_lds's
// wave-uniform-base + lane*16 dest contiguity matches the global layout.
__global__ __launch_bounds__(256) void gemm_qkv(
    const unsigned short* __restrict__ Xb,   // [M_,512] bf16
    const unsigned short* __restrict__ Wt,   // [N_,512] bf16
    const float* __restrict__ bq, const float* __restrict__ bk2,
    const float* __restrict__ bv,
    unsigned short* __restrict__ Cb)         // [M_,N_] bf16
{
    __shared__ unsigned short As[128 * 32];
    __shared__ unsigned short Bs[128 * 32];
    const int tid = threadIdx.x;
    const int m0 = blockIdx.y * 128;
    const int n0 = blockIdx.x * 128;
    const int wave = tid >> 6, lane = tid & 63;
    const int wm = (wave >> 1) << 6, wn = (wave & 1) << 6;
    const int qd = lane >> 4, r16 = lane & 15;

    // staging: wave w covers rows [32w,32w+32), two 16-row issues each of A,B
    const int arow = wave * 32 + (lane >> 2);      // per-lane row, issue 0
    const int acol = (lane & 3) * 8;               // per-lane col (8 bf16 = 16B)
    const unsigned short* ag = Xb + (size_t)(m0 + arow) * D_ + acol;
    const unsigned short* bg = Wt + (size_t)(n0 + arow) * D_ + acol;
    unsigned short* al = As + (wave * 32) * 32;    // wave-uniform LDS base
    unsigned short* bl = Bs + (wave * 32) * 32;

    floatx4 acc[4][4] = {};

    for (int kc = 0; kc < D_; kc += 32) {
        async16(ag + kc,         al);
        async16(ag + 16*D_ + kc, al + 16*32);
        async16(bg + kc,         bl);
        async16(bg + 16*D_ + kc, bl + 16*32);
        __syncthreads();                            // drains vmcnt before barrier

        short8 af[4], bf[4];
#pragma unroll
        for (int mi = 0; mi < 4; mi++)
            af[mi] = __builtin_bit_cast(short8,
                *(const uint4*)(As + (wm + mi*16 + r16)*32 + qd*8));
#pragma unroll
        for (int ni = 0; ni < 4; ni++)
            bf[ni] = __builtin_bit_cast(short8,
                *(const uint4*)(Bs + (wn + ni*16 + r16)*32 + qd*8));
#pragma unroll
        for (int mi = 0; mi < 4; mi++)
#pragma unroll
            for (int ni = 0; ni < 4; ni++)
                acc[mi][ni] = __builtin_amdgcn_mfma_f32_16x16x32_bf16(
                    af[mi], bf[ni], acc[mi][ni], 0, 0, 0);
        __syncthreads();
    }

    // epilogue: +bias, store bf16.  C/D layout: col=lane&15, row=(lane>>4)*4+r
#pragma unroll
    for (int ni = 0; ni < 4; ni++) {
        int col = n0 + wn + ni*16 + r16;
        float bias = (col < 512) ? bq[col] : ((col < 1024) ? bk2[col - 512] : bv[col - 1024]);
#pragma unroll
        for (int mi = 0; mi < 4; mi++) {
#pragma unroll
            for (int r = 0; r < 4; r++) {
                int row = m0 + wm + mi*16 + qd*4 + r;
                Cb[(size_t)row * N_ + col] = f2bf(acc[mi][ni][r] + bias);
            }
        }
    }
}

// ---------------- windowed attention (8 lanes per token) ------------------
// lanes c8=0..7 each own 8 channels of one t; K/V loads are 128B contiguous
// per 8-lane group; window dots reduced via __shfl_xor(width=8).
__global__ __launch_bounds__(256) void attn_kernel(
    const unsigned short* __restrict__ Cb,   // [M_,1536] bf16  (Q|K|V)
    const float* __restrict__ Er,            // [8,64,5] fp32
    const int* __restrict__ layer_p,
    float* __restrict__ out,                 // [B_,T_,512] fp32
    float* __restrict__ attn_out)            // [B_,8,T_,5] fp32
{
    __shared__ float sEr[HD_ * W_];
    const int bx = blockIdx.x;               // (b*8+h)*128 + chunk ; T/32=128 chunks
    const int bh = bx >> 7;
    const int chunk = bx & 127;
    const int b = bh >> 3, h = bh & 7;
    const int tid = threadIdx.x;
    const int g = tid >> 3, c8 = tid & 7;
    const int t = chunk * 32 + g;

    for (int i = tid; i < HD_ * W_; i += 256)
        sEr[i] = Er[h * HD_ * W_ + i];
    __syncthreads();

    const int dil = 1 << layer_p[0];
    const int sh = (h < 4) ? 0 : (h == 4 ? -2 : (h == 5 ? -1 : (h == 6 ? 1 : 2)));

    int pos[W_]; bool val[W_];
#pragma unroll
    for (int w = 0; w < W_; w++) {
        pos[w] = t + (sh + w - 2) * dil;
        val[w] = (pos[w] >= 0) && (pos[w] < T_);
    }

    const size_t bT = (size_t)b * T_;
    const unsigned short* qp    = Cb + (bT + t) * N_ + h * HD_ + c8 * 8;
    const unsigned short* kbase = Cb + bT * N_ + 512  + h * HD_ + c8 * 8;
    const unsigned short* vbase = Cb + bT * N_ + 1024 + h * HD_ + c8 * 8;

    float qf[8]; load8bf(qp, qf);

    float s[W_];
#pragma unroll
    for (int w = 0; w < W_; w++) {
        float a = 0.f;
        if (val[w]) {
            float kf[8]; load8bf(kbase + (size_t)pos[w] * N_, kf);
#pragma unroll
            for (int j = 0; j < 8; j++) a = fmaf(qf[j], kf[j], a);
        }
#pragma unroll
        for (int j = 0; j < 8; j++)                 // q . Er partial (masked later)
            a = fmaf(qf[j], sEr[(c8*8 + j) * W_ + w], a);
        s[w] = a;
    }
#pragma unroll
    for (int off = 4; off > 0; off >>= 1)
#pragma unroll
        for (int w = 0; w < W_; w++)
            s[w] += __shfl_xor(s[w], off, 8);

    float logit[W_], mx = -1e30f;
#pragma unroll
    for (int w = 0; w < W_; w++) {
        logit[w] = val[w] ? s[w] * 0.125f : -1e30f;
        mx = fmaxf(mx, logit[w]);
    }
    float p[W_], ssum = 0.f;
#pragma unroll
    for (int w = 0; w < W_; w++) {
        p[w] = val[w] ? __expf(logit[w] - mx) : 0.f;
        ssum += p[w];
    }
    const float inv = 1.f / ssum;
    float aw[W_];
#pragma unroll
    for (int w = 0; w < W_; w++) aw[w] = p[w] * inv;

    if (c8 < W_)
        attn_out[((size_t)(b * H_ + h) * T_ + t) * W_ + c8] = aw[c8];

    float of[8] = {0,0,0,0,0,0,0,0};
#pragma unroll
    for (int w = 0; w < W_; w++) {
        if (val[w]) {
            float vf[8]; load8bf(vbase + (size_t)pos[w] * N_, vf);
#pragma unroll
            for (int j = 0; j < 8; j++) of[j] = fmaf(aw[w], vf[j], of[j]);
        }
    }
    float* orow = out + (bT + t) * D_ + h * HD_ + c8 * 8;
    *(float4*)(orow)     = make_float4(of[0], of[1], of[2], of[3]);
    *(float4*)(orow + 4) = make_float4(of[4], of[5], of[6], of[7]);
}

extern "C" void kernel_launch(void* const* d_in, const int* in_sizes, int n_in,
                              void* d_out, int out_size, void* d_ws, size_t ws_size,
                              hipStream_t stream) {
    const float* x   = (const float*)d_in[0];
    const float* Wq  = (const float*)d_in[1];
    const float* bq  = (const float*)d_in[2];
    const float* Wk  = (const float*)d_in[3];
    const float* bk  = (const float*)d_in[4];
    const float* Wv  = (const float*)d_in[5];
    const float* bv  = (const float*)d_in[6];
    const float* Er  = (const float*)d_in[7];
    const int* layer = (const int*)d_in[8];

    char* ws = (char*)d_ws;
    unsigned short* Xb = (unsigned short*)ws;                               // 16 MB
    unsigned short* Wt = (unsigned short*)(ws + (size_t)16*1024*1024);      // 1.5 MB
    unsigned short* Cb = (unsigned short*)(ws + (size_t)18*1024*1024);      // 48 MB

    float* out  = (float*)d_out;
    float* attn = out + (size_t)B_ * T_ * D_;

    convert_x<<<(M_ * D_ / 8) / 256, 256, 0, stream>>>(x, Xb);
    convert_w<<<(N_ * (D_ / 8)) / 256, 256, 0, stream>>>(Wq, Wk, Wv, Wt);
    dim3 g(N_ / 128, M_ / 128);
    gemm_qkv<<<g, 256, 0, stream>>>(Xb, Wt, bq, bk, bv, Cb);
    attn_kernel<<<(B_ * H_ * T_ * 8) / 256, 256, 0, stream>>>(Cb, Er, layer, out, attn);
}